// Round 5
// baseline (442.702 us; speedup 1.0000x reference)
//
#include <hip/hip_runtime.h>
#include <cstdint>
#include <cstddef>

#define S_LEN 4096
#define DVEC  1024
#define DH    256

typedef __attribute__((ext_vector_type(8))) short short8;
typedef __attribute__((ext_vector_type(4))) float f32x4;
typedef __attribute__((ext_vector_type(4))) unsigned short ushort4v;

__device__ __forceinline__ unsigned short f2bf(float f) {
  unsigned u = __builtin_bit_cast(unsigned, f);
  u += 0x7FFFu + ((u >> 16) & 1u);          // round-to-nearest-even
  return (unsigned short)(u >> 16);
}

__device__ __forceinline__ void gl2lds16(const void* g, void* lds) {
  __builtin_amdgcn_global_load_lds(
      (const __attribute__((address_space(1))) unsigned int*)g,
      (__attribute__((address_space(3))) unsigned int*)lds, 16, 0, 0);
}

// ---------------------------------------------------------------------------
// Kernel 1: weights f32 -> bf16 (wq pre-scaled by 1/sqrt(DH)=1/16).
// ---------------------------------------------------------------------------
__global__ void wcvt_kernel(const float* __restrict__ wq,
                            const float* __restrict__ wk,
                            const float* __restrict__ wv,
                            unsigned short* __restrict__ wbf) {
  int t   = blockIdx.x * 256 + threadIdx.x;
  int idx = t * 4;
  int m   = idx >> 18;
  int off = idx & 262143;
  const float* src = (m == 0) ? wq : (m == 1) ? wk : wv;
  float scale = (m == 0) ? 0.0625f : 1.0f;
  f32x4 v = *(const f32x4*)(src + off);
  ushort4v o;
  o.x = f2bf(v.x * scale);
  o.y = f2bf(v.y * scale);
  o.z = f2bf(v.z * scale);
  o.w = f2bf(v.w * scale);
  *(ushort4v*)(wbf + idx) = o;
}

// ---------------------------------------------------------------------------
// Kernel 2: projection GEMM (unchanged). C = x * W^T + b -> bf16; z==2 -> V^T.
// ---------------------------------------------------------------------------
__global__ void proj_kernel(const float* __restrict__ xq,
                            const float* __restrict__ xk,
                            const float* __restrict__ xv,
                            const unsigned short* __restrict__ wbf,
                            const float* __restrict__ bq,
                            const float* __restrict__ bk,
                            const float* __restrict__ bv,
                            unsigned short* __restrict__ qbf,
                            unsigned short* __restrict__ kbf,
                            unsigned short* __restrict__ vtbf) {
  const int tid  = threadIdx.x;
  const int lane = tid & 63;
  const int w    = tid >> 6;
  const int z    = blockIdx.z;
  const int m0   = blockIdx.x * 64;

  const float* x = (z == 0) ? xq : (z == 1) ? xk : xv;
  const unsigned short* wz = wbf + (size_t)z * (DH * DVEC);
  const float* bias = (z == 0) ? bq : (z == 1) ? bk : bv;
  const float bscale = (z == 0) ? 0.0625f : 1.0f;

  __shared__ float At[2][64 * 32];

  f32x4 zero = {0.f, 0.f, 0.f, 0.f};
  f32x4 acc[4][4];
#pragma unroll
  for (int i = 0; i < 4; ++i)
#pragma unroll
    for (int j = 0; j < 4; ++j) acc[i][j] = zero;

  auto stage = [&](int kt, int buf) {
    char* dstb = (char*)&At[buf][0] + w * 2048;
#pragma unroll
    for (int i = 0; i < 2; ++i) {
      int lin  = w * 2048 + i * 1024 + lane * 16;
      int row  = lin >> 7;
      int scol = (lin ^ ((row & 7) << 4)) & 127;
      gl2lds16((const char*)x + ((size_t)(m0 + row) * DVEC + kt * 32) * 4 + scol,
               dstb + i * 1024);
    }
  };

  stage(0, 0);
  __syncthreads();

  for (int kt = 0; kt < 32; ++kt) {
    const int buf = kt & 1;
    if (kt + 1 < 32) stage(kt + 1, buf ^ 1);

    short8 bfr[4];
#pragma unroll
    for (int cf = 0; cf < 4; ++cf) {
      int h = w * 64 + cf * 16 + (lane & 15);
      int d = kt * 32 + (lane >> 4) * 8;
      bfr[cf] = *(const short8*)(wz + (size_t)h * DVEC + d);
    }
    const char* ab = (const char*)&At[buf][0];
#pragma unroll
    for (int rf = 0; rf < 4; ++rf) {
      int row = rf * 16 + (lane & 15);
      int c0  = row * 128 + (lane >> 4) * 32;
      int sw  = (row & 7) << 4;
      f32x4 v0 = *(const f32x4*)(ab + (c0 ^ sw));
      f32x4 v1 = *(const f32x4*)(ab + ((c0 + 16) ^ sw));
      short8 af;
      af[0] = (short)f2bf(v0.x); af[1] = (short)f2bf(v0.y);
      af[2] = (short)f2bf(v0.z); af[3] = (short)f2bf(v0.w);
      af[4] = (short)f2bf(v1.x); af[5] = (short)f2bf(v1.y);
      af[6] = (short)f2bf(v1.z); af[7] = (short)f2bf(v1.w);
#pragma unroll
      for (int cf = 0; cf < 4; ++cf)
        acc[rf][cf] = __builtin_amdgcn_mfma_f32_16x16x32_bf16(af, bfr[cf], acc[rf][cf], 0, 0, 0);
    }
    __syncthreads();
  }

  float bvv[4];
#pragma unroll
  for (int cf = 0; cf < 4; ++cf)
    bvv[cf] = bias[w * 64 + cf * 16 + (lane & 15)] * bscale;

  if (z < 2) {
    unsigned short* o = (z == 0) ? qbf : kbf;
#pragma unroll
    for (int rf = 0; rf < 4; ++rf)
#pragma unroll
      for (int cf = 0; cf < 4; ++cf)
#pragma unroll
        for (int r = 0; r < 4; ++r) {
          int m = m0 + rf * 16 + (lane >> 4) * 4 + r;
          int h = w * 64 + cf * 16 + (lane & 15);
          o[(size_t)m * DH + h] = f2bf(acc[rf][cf][r] + bvv[cf]);
        }
  } else {
    int bb = m0 >> 12;
    int sl = m0 & 4095;
#pragma unroll
    for (int rf = 0; rf < 4; ++rf)
#pragma unroll
      for (int cf = 0; cf < 4; ++cf) {
        int s = sl + rf * 16 + (lane >> 4) * 4;
        int h = w * 64 + cf * 16 + (lane & 15);
        ushort4v o;
        o.x = f2bf(acc[rf][cf][0] + bvv[cf]);
        o.y = f2bf(acc[rf][cf][1] + bvv[cf]);
        o.z = f2bf(acc[rf][cf][2] + bvv[cf]);
        o.w = f2bf(acc[rf][cf][3] + bvv[cf]);
        *(ushort4v*)(vtbf + ((size_t)(bb * DH + h)) * S_LEN + s) = o;
      }
  }
}

// ---------------------------------------------------------------------------
// Kernel 3: fused masked attention — producer/consumer wave specialization.
// 512 blocks x 512 threads (32 q rows each, 2 blocks/CU, 4 waves/SIMD).
//   Producers w0-3: kvs = w (16-kv slice of the 64-kv tile), all 32 q.
//     QK(t) from LDS K-tile, softmax (no max; scores bounded), write P[t&1].
//   Consumers w4-7: hs = w-4 (64-h slice), all 32 q.
//     PV(t-1): P from LDS, V fragments DIRECT from L2 (coalesced 64B rows,
//     zero redundancy), O accumulates privately (no merge needed).
//   One barrier per tile. K double-buffered via global_load_lds; V unstaged.
// Softmax: p = mask ? exp(s) : 1 (reference fills masked scores with 0
// pre-softmax; exp(0)=1). l partials joined once at the end.
// LDS: K 2x32KB + P 2x4KB + l 0.5KB = 74 KB.
// ---------------------------------------------------------------------------
__global__ void __launch_bounds__(512, 4)
attn_kernel(const unsigned short* __restrict__ qbf,
            const unsigned short* __restrict__ kbf,
            const unsigned short* __restrict__ vtbf,
            const int* __restrict__ mask,
            float* __restrict__ out) {
  const int tid  = threadIdx.x;
  const int lane = tid & 63;
  const int w    = tid >> 6;          // 0..7
  const int j    = lane & 15;
  const int g    = lane >> 4;

  // XCD-aware decode: 512 blocks, blocks on one XCD share a batch
  const int bx = blockIdx.x;
  const int x  = bx & 7;
  const int b  = x >> 1;
  const int qt = (bx >> 3) * 2 + (x & 1);   // 0..127
  const int m0 = qt * 32;

  __shared__ char sbuf[74240];
  // K: buf*32768 [0,65536) ; P: 65536 + buf*4096 ; l: 73728 [32][4] f32
  float* lbuf = (float*)(sbuf + 73728);

  const int NT = S_LEN / 64;   // 64 tiles

  f32x4 zero = {0.f, 0.f, 0.f, 0.f};

  // ---------------- producer state ----------------
  const int kvs = w;                   // 0..3 (valid when w<4)
  short8 qreg[2][8];
  float lrow[2][4] = {{0.f,0.f,0.f,0.f},{0.f,0.f,0.f,0.f}};
  int mcur[8], mnext[8];
  const int* mb = nullptr;
  int pjoff = 0;
  if (w < 4) {
#pragma unroll
    for (int qf = 0; qf < 2; ++qf) {
      const unsigned short* qrow =
          qbf + ((size_t)(b * S_LEN + m0 + qf * 16 + j)) * DH + g * 8;
#pragma unroll
      for (int kc = 0; kc < 8; ++kc) qreg[qf][kc] = *(const short8*)(qrow + kc * 32);
    }
    mb = mask + ((size_t)(b * S_LEN + m0 + g * 4)) * S_LEN + kvs * 16 + j;
    int jj = (kvs & 1) * 16 + j;
    pjoff = (jj >> 3) * 16 + (jj & 7) * 2;
#pragma unroll
    for (int qf = 0; qf < 2; ++qf)
#pragma unroll
      for (int r = 0; r < 4; ++r) mcur[qf * 4 + r] = mb[(qf * 16 + r) * S_LEN];
  }

  // ---------------- consumer state ----------------
  const int hs = w - 4;                // 0..3 (valid when w>=4)
  f32x4 acc[2][4];
#pragma unroll
  for (int a = 0; a < 2; ++a)
#pragma unroll
    for (int hf = 0; hf < 4; ++hf) acc[a][hf] = zero;

  // ---- K staging: 32 slots of 1KB, 4 per wave, wave-uniform LDS dst.
  // Slot rid = kvs_s*8 + kc_s holds, at lane*16:
  //   K[t*64 + kvs_s*16 + (lane&15)][kc_s*32 + (lane>>4)*8 .. +8]
  auto stageK = [&](int t1) {
    const char* src = (const char*)kbf + ((size_t)(b * S_LEN + t1 * 64)) * 512;
    char* dst = sbuf + (t1 & 1) * 32768 + w * 4096;
#pragma unroll
    for (int i = 0; i < 4; ++i) {
      int rid = w * 4 + i;
      int ks  = rid >> 3;
      int kc  = rid & 7;
      gl2lds16(src + (size_t)(ks * 16 + j) * 512 + kc * 64 + g * 16, dst + i * 1024);
    }
  };

  // consumer PV for tile u
  auto pv = [&](int u) {
    const char* pb = sbuf + 65536 + (u & 1) * 4096;
    short8 pf[2][2];
#pragma unroll
    for (int qf2 = 0; qf2 < 2; ++qf2)
#pragma unroll
      for (int kvc = 0; kvc < 2; ++kvc)
        pf[qf2][kvc] = *(const short8*)(pb + (qf2 * 2 + kvc) * 1024 + j * 64 + g * 16);
    const unsigned short* vb =
        vtbf + ((size_t)(b * DH + hs * 64 + j)) * S_LEN + u * 64 + g * 8;
    __builtin_amdgcn_s_setprio(1);
#pragma unroll
    for (int hf = 0; hf < 4; ++hf) {
      short8 v0 = *(const short8*)(vb + (size_t)(hf * 16) * S_LEN);
      short8 v1 = *(const short8*)(vb + (size_t)(hf * 16) * S_LEN + 32);
      acc[0][hf] = __builtin_amdgcn_mfma_f32_16x16x32_bf16(pf[0][0], v0, acc[0][hf], 0, 0, 0);
      acc[1][hf] = __builtin_amdgcn_mfma_f32_16x16x32_bf16(pf[1][0], v0, acc[1][hf], 0, 0, 0);
      acc[0][hf] = __builtin_amdgcn_mfma_f32_16x16x32_bf16(pf[0][1], v1, acc[0][hf], 0, 0, 0);
      acc[1][hf] = __builtin_amdgcn_mfma_f32_16x16x32_bf16(pf[1][1], v1, acc[1][hf], 0, 0, 0);
    }
    __builtin_amdgcn_s_setprio(0);
  };

  // prologue
  stageK(0);
  __syncthreads();

  for (int t = 0; t < NT; ++t) {
    if (t + 1 < NT) stageK(t + 1);     // drains at the end-of-iter barrier

    if (w < 4) {
      // ---- QK(t)
      const char* kb = sbuf + (t & 1) * 32768;
      f32x4 s0 = zero, s1 = zero;
      __builtin_amdgcn_s_setprio(1);
#pragma unroll
      for (int kc = 0; kc < 8; ++kc) {
        short8 kf = *(const short8*)(kb + (kvs * 8 + kc) * 1024 + lane * 16);
        s0 = __builtin_amdgcn_mfma_f32_16x16x32_bf16(qreg[0][kc], kf, s0, 0, 0, 0);
        s1 = __builtin_amdgcn_mfma_f32_16x16x32_bf16(qreg[1][kc], kf, s1, 0, 0, 0);
      }
      __builtin_amdgcn_s_setprio(0);

      if (t + 1 < NT) {
#pragma unroll
        for (int qf = 0; qf < 2; ++qf)
#pragma unroll
          for (int r = 0; r < 4; ++r)
            mnext[qf * 4 + r] = mb[(qf * 16 + r) * S_LEN + (t + 1) * 64];
      }

      // ---- softmax (no max) + P write
      char* pb = sbuf + 65536 + (t & 1) * 4096;
#pragma unroll
      for (int qf = 0; qf < 2; ++qf) {
        int sbase = (qf * 2 + (kvs >> 1)) * 1024 + pjoff;
#pragma unroll
        for (int r = 0; r < 4; ++r) {
          float sv = qf ? s1[r] : s0[r];
          sv = mcur[qf * 4 + r] ? sv : 0.0f;
          float e = __expf(sv);
          lrow[qf][r] += e;
          *(unsigned short*)(pb + sbase + (g * 4 + r) * 64) = f2bf(e);
        }
      }
#pragma unroll
      for (int i = 0; i < 8; ++i) mcur[i] = mnext[i];
    } else {
      // ---- PV(t-1)
      if (t > 0) pv(t - 1);
    }

    __syncthreads();
  }

  // epilogue: last PV + l join
  if (w >= 4) {
    pv(NT - 1);
  } else {
#pragma unroll
    for (int qf = 0; qf < 2; ++qf)
#pragma unroll
      for (int r = 0; r < 4; ++r) {
#pragma unroll
        for (int off = 1; off < 16; off <<= 1)
          lrow[qf][r] += __shfl_xor(lrow[qf][r], off, 64);
      }
    if (j == 0) {
#pragma unroll
      for (int qf = 0; qf < 2; ++qf)
#pragma unroll
        for (int r = 0; r < 4; ++r)
          lbuf[(qf * 16 + g * 4 + r) * 4 + kvs] = lrow[qf][r];
    }
  }
  __syncthreads();

  if (w >= 4) {
#pragma unroll
    for (int qf2 = 0; qf2 < 2; ++qf2)
#pragma unroll
      for (int r = 0; r < 4; ++r) {
        f32x4 lv = *(const f32x4*)&lbuf[(qf2 * 16 + g * 4 + r) * 4];
        float linv = 1.0f / (lv[0] + lv[1] + lv[2] + lv[3]);
        float* orow = out + ((size_t)(b * S_LEN + m0 + qf2 * 16 + g * 4 + r)) * DH + hs * 64 + j;
#pragma unroll
        for (int hf = 0; hf < 4; ++hf)
          orow[hf * 16] = acc[qf2][hf][r] * linv;
      }
  }
}

// ---------------------------------------------------------------------------
extern "C" void kernel_launch(void* const* d_in, const int* in_sizes, int n_in,
                              void* d_out, int out_size, void* d_ws, size_t ws_size,
                              hipStream_t stream) {
  const float* xq = (const float*)d_in[0];
  const float* xk = (const float*)d_in[1];
  const float* xv = (const float*)d_in[2];
  const int* mask = (const int*)d_in[3];
  const float* wq = (const float*)d_in[4];
  const float* bq = (const float*)d_in[5];
  const float* wk = (const float*)d_in[6];
  const float* bk = (const float*)d_in[7];
  const float* wv = (const float*)d_in[8];
  const float* bv = (const float*)d_in[9];
  float* out = (float*)d_out;

  char* ws = (char*)d_ws;
  unsigned short* wbf  = (unsigned short*)(ws);                    // 1.5 MB
  unsigned short* qbf  = (unsigned short*)(ws + (2ull  << 20));    // 8 MB
  unsigned short* kbf  = (unsigned short*)(ws + (10ull << 20));    // 8 MB
  unsigned short* vtbf = (unsigned short*)(ws + (18ull << 20));    // 8 MB

  hipLaunchKernelGGL(wcvt_kernel, dim3(768), dim3(256), 0, stream, wq, wk, wv, wbf);
  hipLaunchKernelGGL(proj_kernel, dim3(256, 1, 3), dim3(256), 0, stream,
                     xq, xk, xv, wbf, bq, bk, bv, qbf, kbf, vtbf);
  hipLaunchKernelGGL(attn_kernel, dim3(512), dim3(512), 0, stream,
                     qbf, kbf, vtbf, mask, out);
}